// Round 5
// baseline (324.801 us; speedup 1.0000x reference)
//
#include <hip/hip_runtime.h>
#include <stdint.h>
#include <stddef.h>

#define B_  16
#define U_  512
#define LX_ 1024
#define LY_ 1024
#define H_  8
#define D_  64

typedef unsigned short ushort_t;
typedef unsigned int   uint_t;
typedef __bf16 v8bf  __attribute__((ext_vector_type(8)));
typedef float  v16f  __attribute__((ext_vector_type(16)));
typedef float  v2f   __attribute__((ext_vector_type(2)));

__device__ __forceinline__ ushort_t bf16u(float f) {
    uint_t u = __float_as_uint(f);
    uint_t r = (u + 0x7FFFu + ((u >> 16) & 1u)) >> 16;
    return (ushort_t)r;
}
__device__ __forceinline__ float bfu2f(ushort_t u) {
    return __uint_as_float(((uint_t)u) << 16);
}
// RNE-pack two fp32 -> packed bf16x2 (low=f0).
__device__ __forceinline__ uint_t pkbf16(float f0, float f1) {
    uint_t u0 = __float_as_uint(f0), u1 = __float_as_uint(f1);
    u0 = u0 + 0x7FFFu + ((u0 >> 16) & 1u);
    u1 = u1 + 0x7FFFu + ((u1 >> 16) & 1u);
    return __builtin_amdgcn_perm(u1, u0, 0x07060302u);
}
// TRUNCATING pack (epilogue scale absorbs; P-matrix only): 1 op.
__device__ __forceinline__ uint_t pkbf16_trunc(float f0, float f1) {
    return __builtin_amdgcn_perm(__float_as_uint(f1), __float_as_uint(f0), 0x07060302u);
}
// async global->LDS, 16B/lane. LDS dest is wave-uniform base + lane*16, so
// swizzling must be applied to the GLOBAL source chunk, not the LDS address.
__device__ __forceinline__ void gload16(const void* g, void* l) {
    auto gp = (const __attribute__((address_space(1))) uint32_t*)(uintptr_t)g;
    auto lp = (__attribute__((address_space(3))) uint32_t*)(uintptr_t)l;
    __builtin_amdgcn_global_load_lds(gp, lp, 16, 0, 0);
}

// ---------------------------------------------------------------------------
// Detect mask element width: int32 (all first-1024 words <= 1) vs uint8.
// ---------------------------------------------------------------------------
__global__ void detect_kernel(const uint_t* __restrict__ mask, int* __restrict__ flag) {
    __shared__ int s;
    if (threadIdx.x == 0) s = 0;
    __syncthreads();
    int c = 0;
    for (int i = threadIdx.x; i < 1024; i += 256) c += (mask[i] <= 1u) ? 1 : 0;
    atomicAdd(&s, c);
    __syncthreads();
    if (threadIdx.x == 0) *flag = (s >= 1000) ? 1 : 0;
}

// ---------------------------------------------------------------------------
// Single mask pass: maskBits (ballot) + n_el (popcount). One wave per row.
// ---------------------------------------------------------------------------
__global__ __launch_bounds__(256) void nelmask_kernel(const void* __restrict__ mask,
                                                      const int* __restrict__ flag,
                                                      float* __restrict__ nel,
                                                      uint_t* __restrict__ mb) {
    int row  = blockIdx.x * 4 + (threadIdx.x >> 6);   // b*1024 + x
    int lane = threadIdx.x & 63;
    const int isInt = *flag;
    const uint8_t* m8  = (const uint8_t*)mask + (size_t)row * LY_;
    const int*     m32 = (const int*)mask + (size_t)row * LY_;
    int cnt = 0;
    for (int yg = 0; yg < LY_ / 64; ++yg) {
        int y = yg * 64 + lane;
        bool p = isInt ? (m32[y] != 0) : (m8[y] != 0);
        unsigned long long bal = __ballot(p);
        if (lane == 0) {
            mb[(size_t)row * 32 + yg * 2]     = (uint_t)bal;
            mb[(size_t)row * 32 + yg * 2 + 1] = (uint_t)(bal >> 32);
            cnt += __popcll(bal);
        }
    }
    if (lane == 0) nel[row] = (float)(cnt > 0 ? cnt : 1);
}

// ---------------------------------------------------------------------------
// All three 512x512 weights -> bf16 in one dispatch (blockIdx.y selects).
// ---------------------------------------------------------------------------
__global__ __launch_bounds__(256) void castw_kernel(const float* __restrict__ w0,
                                                    const float* __restrict__ w1,
                                                    const float* __restrict__ w2,
                                                    ushort_t* __restrict__ o0,
                                                    ushort_t* __restrict__ o1,
                                                    ushort_t* __restrict__ o2) {
    const float* s = blockIdx.y == 0 ? w0 : (blockIdx.y == 1 ? w1 : w2);
    ushort_t*    d = blockIdx.y == 0 ? o0 : (blockIdx.y == 1 ? o1 : o2);
    int i = (blockIdx.x * 256 + threadIdx.x) * 4;
    float4 v = *(const float4*)&s[i];
    ushort4 p;
    p.x = bf16u(v.x); p.y = bf16u(v.y); p.z = bf16u(v.z); p.w = bf16u(v.w);
    *(ushort4*)&d[i] = p;
}

// ---------------------------------------------------------------------------
// x and y [b][u][l] fp32 -> [b][l][u] bf16, 64x64 LDS tiles. z = b + 16*sel.
// ---------------------------------------------------------------------------
__global__ __launch_bounds__(256) void castT_kernel(const float* __restrict__ X,
                                                    const float* __restrict__ Y,
                                                    ushort_t* __restrict__ XT,
                                                    ushort_t* __restrict__ YT) {
    const int l0 = blockIdx.x * 64;
    const int u0 = blockIdx.y * 64;
    const int b  = blockIdx.z & 15;
    const int sel = blockIdx.z >> 4;
    const float* S = sel ? Y : X;
    ushort_t*  Dst = sel ? YT : XT;
    __shared__ ushort_t T[64][72];
    const int tid = threadIdx.x;
    #pragma unroll
    for (int e = 0; e < 4; ++e) {
        int ci = e * 256 + tid;            // 0..1023 float4s
        int r = ci >> 4, c4 = (ci & 15) * 4;
        float4 v = *(const float4*)&S[((size_t)(b * U_ + u0 + r) << 10) + l0 + c4];
        T[r][c4 + 0] = bf16u(v.x); T[r][c4 + 1] = bf16u(v.y);
        T[r][c4 + 2] = bf16u(v.z); T[r][c4 + 3] = bf16u(v.w);
    }
    __syncthreads();
    #pragma unroll
    for (int e = 0; e < 2; ++e) {
        int ci = e * 256 + tid;            // 0..511 chunks of 8
        int lr = ci >> 3, cc = ci & 7;
        ushort_t tmp[8];
        #pragma unroll
        for (int j = 0; j < 8; ++j) tmp[j] = T[cc * 8 + j][lr];
        *(uint4*)&Dst[((size_t)((b << 10) + l0 + lr)) * U_ + u0 + cc * 8] = *(uint4*)tmp;
    }
}

// ---------------------------------------------------------------------------
// Generalized bf16 MFMA GEMM: Out[b][m][n] = sum_k A_b[m][k] * B_b[n][k]
// K = 512. 128x128 tile, BK=64, gload16 staging, src-xor swizzle.
// ---------------------------------------------------------------------------
template <int OUTF32>
__global__ __launch_bounds__(256) void gemm_mfma(const ushort_t* __restrict__ A, size_t aStr,
                                                 const ushort_t* __restrict__ Bm, size_t bStr,
                                                 void* __restrict__ Out, size_t oStr, int ldOut) {
    const int n0 = blockIdx.x * 128;
    const int m0 = blockIdx.y * 128;
    const int b  = blockIdx.z;
    __shared__ __align__(16) ushort_t As[128 * 64];
    __shared__ __align__(16) ushort_t Bs[128 * 64];
    const int tid = threadIdx.x;
    const ushort_t* Ab = A + aStr * b;
    const ushort_t* Bb = Bm + bStr * b;

    const int w = tid >> 6, lane = tid & 63, lo = lane & 31, hi = lane >> 5;
    const int wm = (w >> 1) * 64, wn = (w & 1) * 64;

    v16f acc00, acc01, acc10, acc11;
    #pragma unroll
    for (int i = 0; i < 16; ++i) { acc00[i] = 0.f; acc01[i] = 0.f; acc10[i] = 0.f; acc11[i] = 0.f; }

    for (int kk = 0; kk < 8; ++kk) {
        const int k0 = kk * 64;
        #pragma unroll
        for (int e = 0; e < 4; ++e) {
            int ci = e * 256 + tid;          // 0..1023 16B chunks
            int r = ci >> 3, c = ci & 7;
            int g = (c ^ (r & 7)) << 3;      // swizzle on SOURCE chunk
            gload16(&Ab[(size_t)(m0 + r) * U_ + k0 + g], &As[ci * 8]);
            gload16(&Bb[(size_t)(n0 + r) * U_ + k0 + g], &Bs[ci * 8]);
        }
        __syncthreads();
        #pragma unroll
        for (int ks = 0; ks < 4; ++ks) {
            int ch = ks * 2 + hi;
            int rA0 = wm + lo, rA1 = wm + 32 + lo;
            int rB0 = wn + lo, rB1 = wn + 32 + lo;
            v8bf a0 = *(v8bf*)&As[rA0 * 64 + ((ch ^ (rA0 & 7)) << 3)];
            v8bf a1 = *(v8bf*)&As[rA1 * 64 + ((ch ^ (rA1 & 7)) << 3)];
            v8bf b0 = *(v8bf*)&Bs[rB0 * 64 + ((ch ^ (rB0 & 7)) << 3)];
            v8bf b1 = *(v8bf*)&Bs[rB1 * 64 + ((ch ^ (rB1 & 7)) << 3)];
            acc00 = __builtin_amdgcn_mfma_f32_32x32x16_bf16(a0, b0, acc00, 0, 0, 0);
            acc01 = __builtin_amdgcn_mfma_f32_32x32x16_bf16(a0, b1, acc01, 0, 0, 0);
            acc10 = __builtin_amdgcn_mfma_f32_32x32x16_bf16(a1, b0, acc10, 0, 0, 0);
            acc11 = __builtin_amdgcn_mfma_f32_32x32x16_bf16(a1, b1, acc11, 0, 0, 0);
        }
        __syncthreads();
    }

    #pragma unroll
    for (int mi = 0; mi < 2; ++mi) {
        #pragma unroll
        for (int nj = 0; nj < 2; ++nj) {
            v16f c = mi ? (nj ? acc11 : acc10) : (nj ? acc01 : acc00);
            int n = n0 + wn + nj * 32 + lo;
            #pragma unroll
            for (int r = 0; r < 16; ++r) {
                int m = m0 + wm + mi * 32 + (r & 3) + 8 * (r >> 2) + 4 * hi;
                size_t addr = oStr * b + (size_t)m * ldOut + n;
                if (OUTF32) ((float*)Out)[addr] = c[r];
                else        ((ushort_t*)Out)[addr] = bf16u(c[r]);
            }
        }
    }
}

// ---------------------------------------------------------------------------
// K-GEMM with fused dual-layout epilogue:
//   Ka[b][u][y] = wk[u][k] . yT[b][y][k]   (direct store, as gemm_mfma)
//   Kb[b][h][y][d]                         (via in-LDS transpose over As/Bs)
// grid (8 = Ly/128, 4 = U/128, B). m = u, n = y.
// ---------------------------------------------------------------------------
__global__ __launch_bounds__(256) void gemm_k(const ushort_t* __restrict__ A,
                                              const ushort_t* __restrict__ Bm,
                                              ushort_t* __restrict__ Ka,
                                              ushort_t* __restrict__ Kb) {
    const int n0 = blockIdx.x * 128;   // y
    const int m0 = blockIdx.y * 128;   // u
    const int b  = blockIdx.z;
    __shared__ __align__(16) ushort_t SM[128 * 128];   // As | Bs, then T
    ushort_t* As = SM;
    ushort_t* Bs = SM + 128 * 64;
    const int tid = threadIdx.x;
    const ushort_t* Bb = Bm + ((size_t)b << 10) * U_;

    const int w = tid >> 6, lane = tid & 63, lo = lane & 31, hi = lane >> 5;
    const int wm = (w >> 1) * 64, wn = (w & 1) * 64;

    v16f acc00, acc01, acc10, acc11;
    #pragma unroll
    for (int i = 0; i < 16; ++i) { acc00[i] = 0.f; acc01[i] = 0.f; acc10[i] = 0.f; acc11[i] = 0.f; }

    for (int kk = 0; kk < 8; ++kk) {
        const int k0 = kk * 64;
        #pragma unroll
        for (int e = 0; e < 4; ++e) {
            int ci = e * 256 + tid;
            int r = ci >> 3, c = ci & 7;
            int g = (c ^ (r & 7)) << 3;
            gload16(&A[(size_t)(m0 + r) * U_ + k0 + g], &As[ci * 8]);
            gload16(&Bb[(size_t)(n0 + r) * U_ + k0 + g], &Bs[ci * 8]);
        }
        __syncthreads();
        #pragma unroll
        for (int ks = 0; ks < 4; ++ks) {
            int ch = ks * 2 + hi;
            int rA0 = wm + lo, rA1 = wm + 32 + lo;
            int rB0 = wn + lo, rB1 = wn + 32 + lo;
            v8bf a0 = *(v8bf*)&As[rA0 * 64 + ((ch ^ (rA0 & 7)) << 3)];
            v8bf a1 = *(v8bf*)&As[rA1 * 64 + ((ch ^ (rA1 & 7)) << 3)];
            v8bf b0 = *(v8bf*)&Bs[rB0 * 64 + ((ch ^ (rB0 & 7)) << 3)];
            v8bf b1 = *(v8bf*)&Bs[rB1 * 64 + ((ch ^ (rB1 & 7)) << 3)];
            acc00 = __builtin_amdgcn_mfma_f32_32x32x16_bf16(a0, b0, acc00, 0, 0, 0);
            acc01 = __builtin_amdgcn_mfma_f32_32x32x16_bf16(a0, b1, acc01, 0, 0, 0);
            acc10 = __builtin_amdgcn_mfma_f32_32x32x16_bf16(a1, b0, acc10, 0, 0, 0);
            acc11 = __builtin_amdgcn_mfma_f32_32x32x16_bf16(a1, b1, acc11, 0, 0, 0);
        }
        __syncthreads();   // last iter: also licenses SM reuse as T below
    }

    // Epilogue A: Ka[b][u][y] scalar bf16 (lanes = consecutive y, coalesced)
    // Epilogue B: T[y_l][u_l] in LDS (rot-32 swizzle on 4-elem chunks), then
    //             coalesced uint4 store to Kb[b][h][y][d].
    #pragma unroll
    for (int mi = 0; mi < 2; ++mi) {
        #pragma unroll
        for (int nj = 0; nj < 2; ++nj) {
            v16f c = mi ? (nj ? acc11 : acc10) : (nj ? acc01 : acc00);
            int y_l = wn + nj * 32 + lo;
            int n = n0 + y_l;
            #pragma unroll
            for (int r = 0; r < 16; ++r) {
                int m = m0 + wm + mi * 32 + (r & 3) + 8 * (r >> 2) + 4 * hi;
                Ka[((size_t)(b * U_ + m) << 10) + n] = bf16u(c[r]);
            }
            #pragma unroll
            for (int q = 0; q < 4; ++q) {
                int u4 = wm + mi * 32 + 8 * q + 4 * hi;     // multiple of 4
                int c4 = u4 >> 2;
                int col = ((c4 + (y_l & 31)) & 31) * 4;
                uint2 pk;
                pk.x = pkbf16(c[4 * q + 0], c[4 * q + 1]);
                pk.y = pkbf16(c[4 * q + 2], c[4 * q + 3]);
                *(uint2*)&SM[y_l * 128 + col] = pk;
            }
        }
    }
    __syncthreads();
    #pragma unroll
    for (int e = 0; e < 8; ++e) {
        int idx = e * 256 + tid;           // 0..2047
        int row = idx >> 4, cc = idx & 15; // y-local, 8-u chunk
        uint2 a = *(const uint2*)&SM[row * 128 + (((2 * cc)     + (row & 31) & 31)) * 4];
        uint2 bq = *(const uint2*)&SM[row * 128 + (((2 * cc + 1) + (row & 31) & 31)) * 4];
        uint4 v = make_uint4(a.x, a.y, bq.x, bq.y);
        int ug = m0 + cc * 8;
        int h = ug >> 6, d = ug & 63;
        *(uint4*)&Kb[(((size_t)(b * H_ + h) << 10) + n0 + row) * D_ + d] = v;
    }
}

// ---------------------------------------------------------------------------
// Fused bf16-MFMA attention. QT[b][x][u] bf16 in, ET[b][x][u] bf16 out.
// 1-D grid of 1024: bh = id&127 (XCD-grouped), xt = id>>7. 256 thr.
// LDS 32 KB (St/Et overlay Qt; Q re-read from global in epilogue) -> 4-5
// blocks/CU. Q fragments hoisted; cheap truncating pack + sbfe masks.
// ---------------------------------------------------------------------------
__global__ __launch_bounds__(256, 4) void attn_mfma(const ushort_t* __restrict__ QTg,
                                                    const ushort_t* __restrict__ Ka_g,
                                                    const ushort_t* __restrict__ Kb_g,
                                                    const uint_t* __restrict__ mbits,
                                                    const float* __restrict__ nel,
                                                    ushort_t* __restrict__ ETg) {
    const int tid = threadIdx.x;
    const int id  = blockIdx.x;
    const int bh  = id & 127;          // same-bh blocks -> same XCD
    const int x0g = (id >> 7) * 128;
    const int b = bh >> 3, h = bh & 7;

    __shared__ __align__(16) ushort_t QS[128 * 64];  // Qt -> St -> Et
    __shared__ __align__(16) ushort_t Kb[64 * 64];
    __shared__ __align__(16) ushort_t Ka[64 * 64];

    const int w    = tid >> 6;
    const int lane = tid & 63;
    const int lo   = lane & 31;
    const int hi   = lane >> 5;
    const int yw   = w & 1;            // S: y-sub;  C: d-sub = yw*32
    const int xws  = (w >> 1) * 64;    // x-subs xws + {0,32}

    // ---- stage Qt[x][d] via gload16 (src-swizzled) ----
    const ushort_t* Qsrc = QTg + ((size_t)(b * LX_ + x0g)) * U_ + h * D_;
    #pragma unroll
    for (int e = 0; e < 4; ++e) {
        int ci = e * 256 + tid;
        int r = ci >> 3, c = ci & 7;
        gload16(&Qsrc[(size_t)r * U_ + ((c ^ (r & 7)) << 3)], &QS[ci * 8]);
    }
    const ushort_t* KaBase = Ka_g + ((size_t)(b * U_ + h * D_)) * LY_;
    const ushort_t* KbBase = Kb_g + ((size_t)(b * H_ + h)) * LY_ * D_;

    __syncthreads();
    // ---- hoist Q B-fragments (loop-invariant): 8 x v8bf = 32 VGPR ----
    v8bf qf0[4], qf1[4];
    const int rB0 = xws + lo, rB1 = xws + 32 + lo;
    #pragma unroll
    for (int kt = 0; kt < 4; ++kt) {
        int ch = kt * 2 + hi;
        qf0[kt] = *(v8bf*)&QS[rB0 * 64 + ((ch ^ (rB0 & 7)) << 3)];
        qf1[kt] = *(v8bf*)&QS[rB1 * 64 + ((ch ^ (rB1 & 7)) << 3)];
    }

    v16f accC0, accC1;
    #pragma unroll
    for (int i = 0; i < 16; ++i) { accC0[i] = 0.f; accC1[i] = 0.f; }

    const int rowA = yw * 32 + lo;
    ushort_t* St = QS;                 // overlay (frags hoisted; Q re-read later)

    for (int y0 = 0; y0 < LY_; y0 += 64) {
        __syncthreads();   // prior C-phase readers done (iter0: frag build done)
        #pragma unroll
        for (int e = 0; e < 2; ++e) {
            int ci = e * 256 + tid;
            int r = ci >> 3, c = ci & 7;
            int g8 = (c ^ (r & 7)) << 3;
            gload16(&KbBase[(size_t)(y0 + r) * D_ + g8], &Kb[ci * 8]);
            gload16(&KaBase[(size_t)r * LY_ + y0 + g8], &Ka[ci * 8]);
        }
        __syncthreads();

        // ---- S-phase: S^T = Kb * Qt^T (B-frags from registers) ----
        v16f s0, s1;
        #pragma unroll
        for (int i = 0; i < 16; ++i) { s0[i] = 0.f; s1[i] = 0.f; }
        #pragma unroll
        for (int kt = 0; kt < 4; ++kt) {
            int ch = kt * 2 + hi;
            v8bf a = *(v8bf*)&Kb[rowA * 64 + ((ch ^ (rowA & 7)) << 3)];
            s0 = __builtin_amdgcn_mfma_f32_32x32x16_bf16(a, qf0[kt], s0, 0, 0, 0);
            s1 = __builtin_amdgcn_mfma_f32_32x32x16_bf16(a, qf1[kt], s1, 0, 0, 0);
        }
        // ---- relu + bitwise mask + truncating pack -> St[x][y] bf16 ----
        #pragma unroll
        for (int i = 0; i < 2; ++i) {
            v16f s = i ? s1 : s0;
            int xl = xws + i * 32 + lo;
            uint_t wbits = mbits[((size_t)(b * LX_ + x0g + xl)) * 32 + (y0 >> 5) + yw];
            #pragma unroll
            for (int g = 0; g < 4; ++g) {
                uint_t w2 = wbits >> (g * 8 + 4 * hi);
                v2f p01 = __builtin_elementwise_max((v2f){s[g * 4 + 0], s[g * 4 + 1]}, (v2f){0.f, 0.f});
                v2f p23 = __builtin_elementwise_max((v2f){s[g * 4 + 2], s[g * 4 + 3]}, (v2f){0.f, 0.f});
                uint_t m0 = (uint_t)__builtin_amdgcn_sbfe(w2, 0, 1);
                uint_t m1 = (uint_t)__builtin_amdgcn_sbfe(w2, 1, 1);
                uint_t m2 = (uint_t)__builtin_amdgcn_sbfe(w2, 2, 1);
                uint_t m3 = (uint_t)__builtin_amdgcn_sbfe(w2, 3, 1);
                uint2 pk;
                pk.x = pkbf16_trunc(p01[0], p01[1]) & __builtin_amdgcn_perm(m1, m0, 0x07060302u);
                pk.y = pkbf16_trunc(p23[0], p23[1]) & __builtin_amdgcn_perm(m3, m2, 0x07060302u);
                int yb = yw * 32 + g * 8 + 4 * hi;
                *(uint2*)&St[xl * 64 + (((yb >> 3) ^ (xl & 7)) << 3) + (yb & 7)] = pk;
            }
        }
        __syncthreads();

        // ---- C-phase: C[d][x] += Ka * St^T ----
        #pragma unroll
        for (int kt = 0; kt < 4; ++kt) {
            int ch = kt * 2 + hi;
            v8bf a  = *(v8bf*)&Ka[rowA * 64 + ((ch ^ (rowA & 7)) << 3)];
            v8bf b0 = *(v8bf*)&St[rB0 * 64 + ((ch ^ (rB0 & 7)) << 3)];
            v8bf b1 = *(v8bf*)&St[rB1 * 64 + ((ch ^ (rB1 & 7)) << 3)];
            accC0 = __builtin_amdgcn_mfma_f32_32x32x16_bf16(a, b0, accC0, 0, 0, 0);
            accC1 = __builtin_amdgcn_mfma_f32_32x32x16_bf16(a, b1, accC1, 0, 0, 0);
        }
    }

    // ---- epilogue: E = 0.5*Q + C*(0.0625/nel); Q re-read from global ----
    __syncthreads();
    ushort_t* Et = QS;
    #pragma unroll
    for (int i = 0; i < 2; ++i) {
        v16f c = i ? accC1 : accC0;
        int xl = xws + i * 32 + lo;
        float invn = 0.0625f / nel[b * LX_ + x0g + xl];
        #pragma unroll
        for (int g = 0; g < 4; ++g) {
            int d0 = yw * 32 + g * 8 + 4 * hi;          // d0&7 == 4*hi
            uint2 qv = *(const uint2*)&Qsrc[(size_t)xl * U_ + d0];
            ushort_t q4[4];
            *(uint2*)q4 = qv;
            ushort_t e4[4];
            #pragma unroll
            for (int r4 = 0; r4 < 4; ++r4) {
                float e = 0.5f * bfu2f(q4[r4]) + c[g * 4 + r4] * invn;
                e4[r4] = bf16u(e);
            }
            *(uint2*)&Et[xl * 64 + ((((d0 >> 3) ^ (xl & 7)) << 3) | (d0 & 7))] = *(uint2*)e4;
        }
    }
    __syncthreads();
    // ---- write ET[b][x][h*64+d] coalesced (un-swizzle on read) ----
    #pragma unroll
    for (int e = 0; e < 4; ++e) {
        int idx = e * 256 + tid;
        int row = idx >> 3, cc = idx & 7;
        uint4 v = *(const uint4*)&Et[row * 64 + ((cc ^ (row & 7)) << 3)];
        *(uint4*)&ETg[((size_t)(b * LX_ + x0g + row)) * U_ + h * D_ + cc * 8] = v;
    }
}

// ---------------------------------------------------------------------------
extern "C" void kernel_launch(void* const* d_in, const int* in_sizes, int n_in,
                              void* d_out, int out_size, void* d_ws, size_t ws_size,
                              hipStream_t stream) {
    const float* x    = (const float*)d_in[0];
    const float* y    = (const float*)d_in[1];
    const void*  mask = d_in[2];
    const float* wq   = (const float*)d_in[3];
    const float* wk   = (const float*)d_in[4];
    const float* wo   = (const float*)d_in[5];

    // ws layout (bytes):
    //   [0,        16777216)  xT bf16   -> later Kb bf16 (xT dead after Q-GEMM)
    //   [16777216, 33554432)  yT bf16   -> later ET bf16 (yT dead after K-GEMM)
    //   [33554432, 50331648)  Ka bf16
    //   [50331648, 50855936)  wq bf16
    //   [50855936, 51380224)  wk bf16
    //   [51380224, 51904512)  wo bf16
    //   [51904512, 54001664)  maskBits u32
    //   [54001664, 54067200)  nel f32
    //   [54067200, ...)       flag int
    char* wsb = (char*)d_ws;
    ushort_t* xT    = (ushort_t*)(wsb);
    ushort_t* yT    = (ushort_t*)(wsb + 16777216);
    ushort_t* Ka    = (ushort_t*)(wsb + 33554432);
    ushort_t* wqb   = (ushort_t*)(wsb + 50331648);
    ushort_t* wkb   = (ushort_t*)(wsb + 50855936);
    ushort_t* wob   = (ushort_t*)(wsb + 51380224);
    uint_t*   mbits = (uint_t*)(wsb + 51904512);
    float*    nel   = (float*)(wsb + 54001664);
    int*      flag  = (int*)(wsb + 54067200);
    ushort_t* Kb    = xT;                 // alias: xT dead after Q-GEMM
    ushort_t* ET    = yT;                 // alias: yT dead after K-GEMM
    ushort_t* QT    = (ushort_t*)d_out;   // QT[b][x][u] bf16 lives in d_out

    detect_kernel<<<1, 256, 0, stream>>>((const uint_t*)mask, flag);
    nelmask_kernel<<<(B_ * LX_) / 4, 256, 0, stream>>>(mask, flag, nel, mbits);
    castw_kernel<<<dim3(U_ * U_ / 1024, 3), 256, 0, stream>>>(wq, wk, wo, wqb, wkb, wob);
    castT_kernel<<<dim3(16, 8, 32), 256, 0, stream>>>(x, y, xT, yT);

    // QT[b][x][u] = xT[b] (M=1024) x wq (N=512)   -- must precede Kb (aliases xT)
    gemm_mfma<0><<<dim3(4, 8, B_), 256, 0, stream>>>(
        xT, (size_t)LX_ * U_, wqb, 0, (void*)QT, (size_t)LX_ * U_, U_);
    // Ka[b][u][y] + Kb[b][h][y][d] = wk (M=512) x yT[b] (N=1024), fused epilogue
    gemm_k<<<dim3(8, 4, B_), 256, 0, stream>>>(wkb, yT, Ka, Kb);
    attn_mfma<<<1024, 256, 0, stream>>>(QT, Ka, Kb, mbits, nel, ET);
    // out[b][u][x] fp32 = wo (M=512) x ET[b] (N=1024)
    gemm_mfma<1><<<dim3(8, 4, B_), 256, 0, stream>>>(
        wob, 0, ET, (size_t)LX_ * U_, d_out, (size_t)U_ * LX_, LX_);
}